// Round 9
// baseline (366.709 us; speedup 1.0000x reference)
//
#include <hip/hip_runtime.h>

#define N_OCC   20000
#define N_SKILL 50000
#define N_EDGE  600000
#define D_IN    256
#define HID     128
#define OUT_F   64

typedef short bf16x8 __attribute__((ext_vector_type(8)));
typedef float f32x4  __attribute__((ext_vector_type(4)));

__device__ __forceinline__ float bf2f(unsigned short u){
  return __uint_as_float(((unsigned)u) << 16);
}
__device__ __forceinline__ unsigned f2bf_bits(float f){
  unsigned i = __float_as_uint(f);
  return (i + 0x7fffu + ((i >> 16) & 1u)) >> 16;   // RNE
}
__device__ __forceinline__ unsigned f2bf_bits_u(unsigned i){
  return (i + 0x7fffu + ((i >> 16) & 1u)) >> 16;   // RNE from raw f32 bits
}
__device__ __forceinline__ unsigned short f2bf(float f){ return (unsigned short)f2bf_bits(f); }

// async global->LDS, 16B per lane. LDS dest must be linear in lane (wave-uniform
// base + lane*16); global src may be fully per-lane (m173: pre-swizzled source).
__device__ __forceinline__ void gload_lds16(const void* g, void* l){
  __builtin_amdgcn_global_load_lds(
      (const __attribute__((address_space(1))) unsigned int*)g,
      (__attribute__((address_space(3))) unsigned int*)l, 16, 0, 0);
}

// ---------- canonicalize float tensors to bf16 (self-detecting wire dtype) ----------
// x tensors (isx=1) converted ONLY on the f32 path. Block 0 publishes the flag
// for downstream kernels (GEMM A-select, output dtype).
#define NT_CONV 18
struct ConvTable {
  const void*     src[NT_CONV];
  unsigned short* dst[NT_CONV];
  int             n[NT_CONV];
  int             isx[NT_CONV];
  int             blk_off[NT_CONV + 1];   // cumulative blocks (2048 elems/block)
};

__global__ void k_convert(ConvTable t, const unsigned short* __restrict__ xprobe,
                          int* __restrict__ flag){
  __shared__ int wsum[4];
  int tid = threadIdx.x;
  // self-detect: f32 low-mantissa halves have random exponent fields
  int cnt = 0;
  for (int i = tid; i < 1024; i += 256){
    unsigned e = ((unsigned)xprobe[i] >> 7) & 0xFFu;
    if (e >= 0xE0u) cnt++;
  }
  #pragma unroll
  for (int s = 1; s < 64; s <<= 1) cnt += __shfl_xor(cnt, s, 64);
  if ((tid & 63) == 0) wsum[tid >> 6] = cnt;
  __syncthreads();
  int isf32 = (wsum[0] + wsum[1] + wsum[2] + wsum[3]) >= 8;
  if (blockIdx.x == 0 && tid == 0) *flag = isf32;

  int b = blockIdx.x;
  int ti = 0;
  while (ti < NT_CONV - 1 && b >= t.blk_off[ti + 1]) ti++;
  if (!isf32 && t.isx[ti]) return;               // bf16 wire: x read in-place
  int lb = b - t.blk_off[ti];
  int i = (lb * 256 + tid) * 8;                  // element index (8 per thread)
  if (i >= t.n[ti]) return;
  unsigned short* dst = t.dst[ti];
  if (isf32){
    const float* s = (const float*)t.src[ti];
    uint4 lo = *(const uint4*)(s + i);
    uint4 hi = *(const uint4*)(s + i + 4);
    uint4 o;
    o.x = f2bf_bits_u(lo.x) | (f2bf_bits_u(lo.y) << 16);
    o.y = f2bf_bits_u(lo.z) | (f2bf_bits_u(lo.w) << 16);
    o.z = f2bf_bits_u(hi.x) | (f2bf_bits_u(hi.y) << 16);
    o.w = f2bf_bits_u(hi.z) | (f2bf_bits_u(hi.w) << 16);
    *(uint4*)(dst + i) = o;
  } else {
    *(uint4*)(dst + i) = *(const uint4*)((const unsigned short*)t.src[ti] + i);
  }
}

// ---------- transpose weight matrices W[K][N] -> WT[N][K] ----------
__global__ void k_transpose_all(
    const unsigned short* pWo, unsigned short* tWo,   // 256x128
    const unsigned short* pWs, unsigned short* tWs,   // 256x128
    const unsigned short* w2,  unsigned short* t2,    // 128x128
    const unsigned short* w3,  unsigned short* t3,
    const unsigned short* w4,  unsigned short* t4,
    const unsigned short* w5,  unsigned short* t5,
    const unsigned short* w6,  unsigned short* t6,    // 128x64
    const unsigned short* w7,  unsigned short* t7,
    const unsigned short* w8,  unsigned short* t8,
    const unsigned short* w9,  unsigned short* t9)
{
  int idx = blockIdx.x * blockDim.x + threadIdx.x;
  const unsigned short* in; unsigned short* out; int K, N, base;
  if      (idx <  32768){ in=pWo; out=tWo; K=256; N=128; base=0; }
  else if (idx <  65536){ in=pWs; out=tWs; K=256; N=128; base=32768; }
  else if (idx <  81920){ in=w2;  out=t2;  K=128; N=128; base=65536; }
  else if (idx <  98304){ in=w3;  out=t3;  K=128; N=128; base=81920; }
  else if (idx < 114688){ in=w4;  out=t4;  K=128; N=128; base=98304; }
  else if (idx < 131072){ in=w5;  out=t5;  K=128; N=128; base=114688; }
  else if (idx < 139264){ in=w6;  out=t6;  K=128; N=64;  base=131072; }
  else if (idx < 147456){ in=w7;  out=t7;  K=128; N=64;  base=139264; }
  else if (idx < 155648){ in=w8;  out=t8;  K=128; N=64;  base=147456; }
  else if (idx < 163840){ in=w9;  out=t9;  K=128; N=64;  base=155648; }
  else return;
  int li = idx - base;
  int k = li / N, n = li - k * N;
  out[n * K + k] = in[li];
}

// ---------- CSR build: bucket counting sort, no node-level global atomics ----------
#define EPB      4096
#define BIN_BLKS ((N_EDGE + EPB - 1) / EPB)         // 147
#define SH_S 9
#define SH_O 8
#define NB_S ((N_SKILL + (1 << SH_S) - 1) >> SH_S)  // 98
#define NB_O ((N_OCC   + (1 << SH_O) - 1) >> SH_O)  // 79

__launch_bounds__(256)
__global__ void k_bincount(const int* __restrict__ eo, const int* __restrict__ es,
                           int* __restrict__ bkcnt_s, int* __restrict__ bkcnt_o)
{
  int b = blockIdx.x;
  int side = (b >= BIN_BLKS) ? 1 : 0;
  int lb = side ? b - BIN_BLKS : b;
  const int* dste = side ? eo : es;
  int* bkcnt = side ? bkcnt_o : bkcnt_s;
  const int NB = side ? NB_O : NB_S;
  const int SH = side ? SH_O : SH_S;
  __shared__ int cntL[NB_S];
  for (int i = threadIdx.x; i < NB; i += 256) cntL[i] = 0;
  __syncthreads();
  int e0 = lb * EPB, e1 = min(e0 + EPB, N_EDGE);
  for (int e = e0 + threadIdx.x; e < e1; e += 256)
    atomicAdd(&cntL[dste[e] >> SH], 1);
  __syncthreads();
  for (int i = threadIdx.x; i < NB; i += 256)
    if (cntL[i]) atomicAdd(&bkcnt[i], cntL[i]);
}

__global__ void k_bscan(const int* __restrict__ bkcnt_s, const int* __restrict__ bkcnt_o,
                        int* __restrict__ boff_s, int* __restrict__ boff_o,
                        int* __restrict__ off_s, int* __restrict__ off_o)
{
  __shared__ int sc[128];
  int t = threadIdx.x;   // 128 threads
  int v = (t < NB_S) ? bkcnt_s[t] : 0;
  sc[t] = v;
  __syncthreads();
  for (int d = 1; d < 128; d <<= 1){
    int u = (t >= d) ? sc[t - d] : 0;
    __syncthreads();
    sc[t] += u;
    __syncthreads();
  }
  if (t < NB_S) boff_s[t] = sc[t] - v;
  if (t == 0){ boff_s[NB_S] = N_EDGE; off_s[N_SKILL] = N_EDGE; }
  __syncthreads();
  int v2 = (t < NB_O) ? bkcnt_o[t] : 0;
  sc[t] = v2;
  __syncthreads();
  for (int d = 1; d < 128; d <<= 1){
    int u = (t >= d) ? sc[t - d] : 0;
    __syncthreads();
    sc[t] += u;
    __syncthreads();
  }
  if (t < NB_O) boff_o[t] = sc[t] - v2;
  if (t == 0){ boff_o[NB_O] = N_EDGE; off_o[N_OCC] = N_EDGE; }
}

// packed pair: (local_dst << 16) | src   (src < 65536, local_dst < 512)
__launch_bounds__(256)
__global__ void k_bin(const int* __restrict__ eo, const int* __restrict__ es,
                      const int* __restrict__ boff_s, const int* __restrict__ boff_o,
                      int* __restrict__ bcur_s, int* __restrict__ bcur_o,
                      unsigned* __restrict__ pair_s, unsigned* __restrict__ pair_o)
{
  int b = blockIdx.x;
  int side = (b >= BIN_BLKS) ? 1 : 0;
  int lb = side ? b - BIN_BLKS : b;
  const int* dste = side ? eo : es;
  const int* srce = side ? es : eo;
  const int* boff = side ? boff_o : boff_s;
  int* bcur       = side ? bcur_o : bcur_s;
  unsigned* pairs = side ? pair_o : pair_s;
  const int NB = side ? NB_O : NB_S;
  const int SH = side ? SH_O : SH_S;

  __shared__ int cntL[NB_S], gbaseL[NB_S], lbaseL[NB_S], runL[NB_S];
  __shared__ int sc[128];
  __shared__ unsigned stage[EPB];   // 16 KB
  __shared__ int gpos[EPB];         // 16 KB

  int e0 = lb * EPB;
  int e1 = min(e0 + EPB, N_EDGE);

  for (int i = threadIdx.x; i < NB; i += 256){ cntL[i] = 0; runL[i] = 0; }
  __syncthreads();
  for (int e = e0 + threadIdx.x; e < e1; e += 256)
    atomicAdd(&cntL[dste[e] >> SH], 1);
  __syncthreads();
  if (threadIdx.x < 128) sc[threadIdx.x] = (threadIdx.x < NB) ? cntL[threadIdx.x] : 0;
  __syncthreads();
  for (int d = 1; d < 128; d <<= 1){
    int v = 0;
    if (threadIdx.x < 128 && threadIdx.x >= d) v = sc[threadIdx.x - d];
    __syncthreads();
    if (threadIdx.x < 128) sc[threadIdx.x] += v;
    __syncthreads();
  }
  if (threadIdx.x < NB){
    int c = cntL[threadIdx.x];
    lbaseL[threadIdx.x] = sc[threadIdx.x] - c;
    gbaseL[threadIdx.x] = boff[threadIdx.x] + atomicAdd(&bcur[threadIdx.x], c);
  }
  __syncthreads();
  for (int e = e0 + threadIdx.x; e < e1; e += 256){
    int d = dste[e], s = srce[e];
    int bk = d >> SH;
    int r = atomicAdd(&runL[bk], 1);
    int lp = lbaseL[bk] + r;
    stage[lp] = ((unsigned)(d & ((1 << SH) - 1)) << 16) | (unsigned)s;
    gpos[lp] = gbaseL[bk] + r;
  }
  __syncthreads();
  int tot = e1 - e0;
  for (int i = threadIdx.x; i < tot; i += 256)
    pairs[gpos[i]] = stage[i];     // consecutive within each bucket run -> coalesced
}

__launch_bounds__(256)
__global__ void k_build(const unsigned* __restrict__ pair_s, const unsigned* __restrict__ pair_o,
                        const int* __restrict__ boff_s, const int* __restrict__ boff_o,
                        int* __restrict__ off_s, int* __restrict__ off_o,
                        int* __restrict__ csr_s, int* __restrict__ csr_o)
{
  int b = blockIdx.x;
  int side = (b >= NB_S) ? 1 : 0;
  int lb = side ? b - NB_S : b;
  const unsigned* pairs = side ? pair_o : pair_s;
  const int* boff = side ? boff_o : boff_s;
  int* off = side ? off_o : off_s;
  int* csr = side ? csr_o : csr_s;
  int SH = side ? SH_O : SH_S;
  int nd_tot = side ? N_OCC : N_SKILL;
  int d0 = lb << SH;
  int d1 = min(d0 + (1 << SH), nd_tot);
  int nd = d1 - d0;
  int p0 = boff[lb], p1 = boff[lb + 1];

  __shared__ int cntL[1 << SH_S];
  __shared__ int offL[1 << SH_S];
  __shared__ int ws[4];
  int t = threadIdx.x;
  cntL[t] = 0; cntL[t + 256] = 0;
  __syncthreads();
  for (int i = p0 + t; i < p1; i += 256)
    atomicAdd(&cntL[pairs[i] >> 16], 1);
  __syncthreads();
  int a0 = cntL[2 * t], a1 = cntL[2 * t + 1];
  int s = a0 + a1;
  int lane = t & 63, wv = t >> 6;
  int x = s;
  #pragma unroll
  for (int d = 1; d < 64; d <<= 1){ int u = __shfl_up(x, d, 64); if (lane >= d) x += u; }
  if (lane == 63) ws[wv] = x;
  __syncthreads();
  int woff = 0;
  for (int w = 0; w < wv; ++w) woff += ws[w];
  int excl = woff + x - s;
  offL[2 * t] = excl;
  offL[2 * t + 1] = excl + a0;
  __syncthreads();
  for (int i = t; i < nd; i += 256) off[d0 + i] = p0 + offL[i];
  cntL[t] = 0; cntL[t + 256] = 0;
  __syncthreads();
  for (int i = p0 + t; i < p1; i += 256){
    unsigned pr = pairs[i];
    int d = (int)(pr >> 16);
    int p = p0 + offL[d] + atomicAdd(&cntL[d], 1);
    csr[p] = (int)(pr & 0xFFFFu);   // scattered only within one L2-resident window
  }
}

// ---------- XCD-sharded segment mean (conv1) ----------
// Gather tables stored CHUNK-MAJOR: fcm[8][nsrc][16] (16 feats = 32B per row).
// Block b handles feature chunk fc = b&7; with round-robin blockIdx->XCD, chunk
// fc's slice (<=1.6MB) is L2-resident on XCD fc -> gathers become L2 hits
// (r8 counters: 90MB fabric at 1.85 TB/s was the seg_mean bottleneck).
// Wave: 8 dst x 4 edge slots x 2 half-chunks (16B/lane), 32 edges in flight.
__launch_bounds__(256)
__global__ void k_seg_mean3(const unsigned short* __restrict__ fcm0,
                            const int* __restrict__ off0, const int* __restrict__ csr0,
                            unsigned short* __restrict__ out0, int n0, int ns0, int nbb0,
                            const unsigned short* __restrict__ fcm1,
                            const int* __restrict__ off1, const int* __restrict__ csr1,
                            unsigned short* __restrict__ out1, int n1, int ns1)
{
  int b = blockIdx.x;
  int side = (b >= nbb0) ? 1 : 0;
  int lb = side ? b - nbb0 : b;            // nbb0 % 8 == 0 keeps fc==XCD across sides
  const unsigned short* fcm = side ? fcm1 : fcm0;
  const int* off = side ? off1 : off0;
  const int* csr = side ? csr1 : csr0;
  unsigned short* out = side ? out1 : out0;
  int n_dst = side ? n1 : n0;
  int nsrc  = side ? ns1 : ns0;
  int fc = lb & 7;
  int g  = lb >> 3;
  int tid = threadIdx.x;
  int lane = tid & 63;
  int wv = tid >> 6;
  int d8 = lane >> 3;          // 8 dst per wave
  int s  = (lane >> 1) & 3;    // 4 edge slots
  int c  = lane & 1;           // 16B half of the 32B chunk
  int gw = g * 32 + wv * 8 + d8;
  if (gw >= n_dst) return;
  const unsigned short* slice = fcm + (size_t)fc * nsrc * 16 + c * 8;
  int beg = off[gw], end = off[gw + 1];
  float acc[8];
  #pragma unroll
  for (int j = 0; j < 8; ++j) acc[j] = 0.0f;
  for (int e = beg + s; e < end; e += 4){
    int si = csr[e];
    uint4 v = *(const uint4*)(slice + (size_t)si * 16);
    acc[0] += __uint_as_float(v.x << 16); acc[1] += __uint_as_float(v.x & 0xffff0000u);
    acc[2] += __uint_as_float(v.y << 16); acc[3] += __uint_as_float(v.y & 0xffff0000u);
    acc[4] += __uint_as_float(v.z << 16); acc[5] += __uint_as_float(v.z & 0xffff0000u);
    acc[6] += __uint_as_float(v.w << 16); acc[7] += __uint_as_float(v.w & 0xffff0000u);
  }
  #pragma unroll
  for (int j = 0; j < 8; ++j){
    acc[j] += __shfl_xor(acc[j], 2, 64);
    acc[j] += __shfl_xor(acc[j], 4, 64);
  }
  if (s == 0){
    int cnt = end - beg;
    float inv = 1.0f / (float)(cnt > 0 ? cnt : 1);
    uint4 o;
    o.x = f2bf_bits(acc[0] * inv) | (f2bf_bits(acc[1] * inv) << 16);
    o.y = f2bf_bits(acc[2] * inv) | (f2bf_bits(acc[3] * inv) << 16);
    o.z = f2bf_bits(acc[4] * inv) | (f2bf_bits(acc[5] * inv) << 16);
    o.w = f2bf_bits(acc[6] * inv) | (f2bf_bits(acc[7] * inv) << 16);
    *(uint4*)(out + (size_t)gw * 128 + fc * 16 + c * 8) = o;   // row-major for GEMM staging
  }
}

// ---------- XCD-sharded conv2 output (8-feat chunks) ----------
// P tables chunk-major: Pcm[16][n][8]. Gather chunks 0..7 (cols 0..63),
// self chunks 8..15 (cols 64..127). out = mean_gather + self + bias.
__launch_bounds__(256)
__global__ void k_seg_out3(const unsigned short* __restrict__ Pg0, const unsigned short* __restrict__ Ps0,
                           const int* __restrict__ off0, const int* __restrict__ csr0,
                           const unsigned short* __restrict__ bias0, size_t o_off0,
                           int n0, int ns0, int nbb0,
                           const unsigned short* __restrict__ Pg1, const unsigned short* __restrict__ Ps1,
                           const int* __restrict__ off1, const int* __restrict__ csr1,
                           const unsigned short* __restrict__ bias1, size_t o_off1,
                           int n1, int ns1,
                           void* __restrict__ out, const int* __restrict__ wire_flag)
{
  int b = blockIdx.x;
  int side = (b >= nbb0) ? 1 : 0;
  int lb = side ? b - nbb0 : b;
  const unsigned short* Pg = side ? Pg1 : Pg0;
  const unsigned short* Ps = side ? Ps1 : Ps0;
  const int* off = side ? off1 : off0;
  const int* csr = side ? csr1 : csr0;
  const unsigned short* bias = side ? bias1 : bias0;
  size_t o_off = side ? o_off1 : o_off0;
  int n_dst = side ? n1 : n0;
  int nsrc  = side ? ns1 : ns0;
  int fc = lb & 7;
  int g  = lb >> 3;
  int tid = threadIdx.x;
  int lane = tid & 63;
  int wv = tid >> 6;
  int d8 = lane >> 3;          // 8 dst per wave
  int s  = lane & 7;           // 8 edge slots, 16B (8 feats) per lane
  int gw = g * 32 + wv * 8 + d8;
  if (gw >= n_dst) return;
  const unsigned short* gsl = Pg + (size_t)fc * nsrc * 8;
  int beg = off[gw], end = off[gw + 1];
  float acc[8];
  #pragma unroll
  for (int j = 0; j < 8; ++j) acc[j] = 0.0f;
  for (int e = beg + s; e < end; e += 8){
    int si = csr[e];
    uint4 v = *(const uint4*)(gsl + (size_t)si * 8);
    acc[0] += __uint_as_float(v.x << 16); acc[1] += __uint_as_float(v.x & 0xffff0000u);
    acc[2] += __uint_as_float(v.y << 16); acc[3] += __uint_as_float(v.y & 0xffff0000u);
    acc[4] += __uint_as_float(v.z << 16); acc[5] += __uint_as_float(v.z & 0xffff0000u);
    acc[6] += __uint_as_float(v.w << 16); acc[7] += __uint_as_float(v.w & 0xffff0000u);
  }
  #pragma unroll
  for (int j = 0; j < 8; ++j){
    acc[j] += __shfl_xor(acc[j], 1, 64);
    acc[j] += __shfl_xor(acc[j], 2, 64);
    acc[j] += __shfl_xor(acc[j], 4, 64);
  }
  if (s == 0){
    int cnt = end - beg;
    float inv = 1.0f / (float)(cnt > 0 ? cnt : 1);
    uint4 sv = *(const uint4*)(Ps + (size_t)(8 + fc) * n_dst * 8 + (size_t)gw * 8);
    uint4 bv = *(const uint4*)(bias + fc * 8);
    float o0 = acc[0] * inv + __uint_as_float(sv.x << 16)         + __uint_as_float(bv.x << 16);
    float o1 = acc[1] * inv + __uint_as_float(sv.x & 0xffff0000u) + __uint_as_float(bv.x & 0xffff0000u);
    float o2 = acc[2] * inv + __uint_as_float(sv.y << 16)         + __uint_as_float(bv.y << 16);
    float o3 = acc[3] * inv + __uint_as_float(sv.y & 0xffff0000u) + __uint_as_float(bv.y & 0xffff0000u);
    float o4 = acc[4] * inv + __uint_as_float(sv.z << 16)         + __uint_as_float(bv.z << 16);
    float o5 = acc[5] * inv + __uint_as_float(sv.z & 0xffff0000u) + __uint_as_float(bv.z & 0xffff0000u);
    float o6 = acc[6] * inv + __uint_as_float(sv.w << 16)         + __uint_as_float(bv.w << 16);
    float o7 = acc[7] * inv + __uint_as_float(sv.w & 0xffff0000u) + __uint_as_float(bv.w & 0xffff0000u);
    size_t eoff = o_off + (size_t)gw * 64 + fc * 8;
    if (*wire_flag){
      float* op = (float*)out + eoff;
      uint4 w0, w1;
      w0.x = __float_as_uint(o0); w0.y = __float_as_uint(o1);
      w0.z = __float_as_uint(o2); w0.w = __float_as_uint(o3);
      w1.x = __float_as_uint(o4); w1.y = __float_as_uint(o5);
      w1.z = __float_as_uint(o6); w1.w = __float_as_uint(o7);
      *(uint4*)op = w0;
      *(uint4*)(op + 4) = w1;
    } else {
      unsigned short* op = (unsigned short*)out + eoff;
      uint4 w;
      w.x = f2bf_bits(o0) | (f2bf_bits(o1) << 16);
      w.y = f2bf_bits(o2) | (f2bf_bits(o3) << 16);
      w.z = f2bf_bits(o4) | (f2bf_bits(o5) << 16);
      w.w = f2bf_bits(o6) | (f2bf_bits(o7) << 16);
      *(uint4*)op = w;
    }
  }
}

// ---------- LDS-staged fused-pair GEMM (r8 structure, +chunk-major epilogue) ----------
// CMODE 0: row-major C only. 1: row-major C + chunk16 CM (proj -> h + h_cm).
// 2: chunk8 CM only (conv2 -> P_cm).
template<int K1, int HASA2, int AW, int CMODE>
__launch_bounds__(256)
__global__ void k_gemm4(const unsigned short* __restrict__ A1a_0, const unsigned short* __restrict__ A1a_1,
                        const unsigned short* __restrict__ A1b_0, const unsigned short* __restrict__ A1b_1,
                        const unsigned short* __restrict__ W1T_0, const unsigned short* __restrict__ W1T_1,
                        const unsigned short* __restrict__ A2_0, const unsigned short* __restrict__ A2_1,
                        const unsigned short* __restrict__ W2T_0, const unsigned short* __restrict__ W2T_1,
                        const unsigned short* __restrict__ bias_0, const unsigned short* __restrict__ bias_1,
                        unsigned short* __restrict__ C_0, unsigned short* __restrict__ C_1,
                        unsigned short* __restrict__ CM_0, unsigned short* __restrict__ CM_1,
                        int ncm0, int ncm1,
                        int nb0, int do_relu, const int* __restrict__ wire_flag)
{
  constexpr int TM    = 80;
  constexpr int ROWB  = K1 * 2;            // bytes per row
  constexpr int TILEB = TM * ROWB;         // bytes per staged tensor tile
  constexpr int ITERS = TILEB / 4096;      // 16B x 256 threads per iter
  constexpr int NK    = K1 / 32;
  constexpr int RSH   = (K1 == 256) ? 9 : 8;

  __shared__ unsigned short lds[(HASA2 ? 2 : 1) * TM * K1];

  int b = blockIdx.x;
  int side = (b >= nb0) ? 1 : 0;
  int lb = side ? b - nb0 : b;
  const unsigned short* A1a = side ? A1a_1 : A1a_0;
  const unsigned short* A1b = side ? A1b_1 : A1b_0;
  const unsigned short* W1T = side ? W1T_1 : W1T_0;
  const unsigned short* A2  = side ? A2_1  : A2_0;
  const unsigned short* W2T = side ? W2T_1 : W2T_0;
  const unsigned short* bias= side ? bias_1: bias_0;
  unsigned short* C  = side ? C_1  : C_0;
  unsigned short* CM = side ? CM_1 : CM_0;
  const size_t ncm = (size_t)(side ? ncm1 : ncm0);

  const unsigned short* A1 = (AW && *wire_flag) ? A1b : A1a;   // f32 wire -> canonical bf16
  const int tid = threadIdx.x;

  // ---- stage A tiles (linear LDS, swizzled global source) ----
  {
    const char* a1base = (const char*)A1 + (size_t)lb * TILEB;
    #pragma unroll
    for (int it = 0; it < ITERS; ++it){
      int L = (it * 256 + tid) * 16;
      int row = L >> RSH;
      int cb  = L & (ROWB - 1);
      int gb  = row * ROWB + (cb ^ ((row & 7) << 4));
      gload_lds16(a1base + gb, (char*)lds + L);
    }
    if (HASA2){
      const char* a2base = (const char*)A2 + (size_t)lb * TILEB;
      #pragma unroll
      for (int it = 0; it < ITERS; ++it){
        int L = (it * 256 + tid) * 16;
        int row = L >> RSH;
        int cb  = L & (ROWB - 1);
        int gb  = row * ROWB + (cb ^ ((row & 7) << 4));
        gload_lds16(a2base + gb, (char*)lds + TILEB + L);
      }
    }
  }

  // ---- B fragments from L2 (overlap the staging drain) ----
  const int lane = tid & 63;
  const int wv   = tid >> 6;       // 32-col group per wave
  const int q    = lane >> 4;
  const int mr   = lane & 15;
  const int koff = q * 8;          // elements

  bf16x8 b1[2][NK];
  #pragma unroll
  for (int nt = 0; nt < 2; ++nt){
    const unsigned short* bp = W1T + (size_t)(wv * 32 + nt * 16 + mr) * K1 + koff;
    #pragma unroll
    for (int k = 0; k < NK; ++k)
      b1[nt][k] = *(const bf16x8*)(bp + k * 32);
  }
  bf16x8 b2[2][HASA2 ? NK : 1];
  if (HASA2){
    #pragma unroll
    for (int nt = 0; nt < 2; ++nt){
      const unsigned short* bp = W2T + (size_t)(wv * 32 + nt * 16 + mr) * K1 + koff;
      #pragma unroll
      for (int k = 0; k < NK; ++k)
        b2[nt][k] = *(const bf16x8*)(bp + k * 32);
    }
  }

  __syncthreads();   // drains vmcnt (incl. global_load_lds) then barrier

  // ---- LDS -> MFMA: 5 row-tiles x 2 col-tiles ----
  f32x4 acc[5][2];
  #pragma unroll
  for (int rt = 0; rt < 5; ++rt)
    #pragma unroll
    for (int nt = 0; nt < 2; ++nt)
      #pragma unroll
      for (int j = 0; j < 4; ++j) acc[rt][nt][j] = 0.0f;

  #pragma unroll
  for (int rt = 0; rt < 5; ++rt){
    const int rl = rt * 16 + mr;
    const int sw = (rl & 7) << 4;
    #pragma unroll
    for (int k = 0; k < NK; ++k){
      const int cb = k * 64 + q * 16;               // bytes within row
      bf16x8 a = *(const bf16x8*)((const char*)lds + rl * ROWB + (cb ^ sw));
      #pragma unroll
      for (int nt = 0; nt < 2; ++nt)
        acc[rt][nt] = __builtin_amdgcn_mfma_f32_16x16x32_bf16(a, b1[nt][k], acc[rt][nt], 0, 0, 0);
      if (HASA2){
        bf16x8 a2 = *(const bf16x8*)((const char*)lds + TILEB + rl * ROWB + (cb ^ sw));
        #pragma unroll
        for (int nt = 0; nt < 2; ++nt)
          acc[rt][nt] = __builtin_amdgcn_mfma_f32_16x16x32_bf16(a2, b2[nt][k], acc[rt][nt], 0, 0, 0);
      }
    }
  }

  // ---- epilogue (no row guards: M % 80 == 0) ----
  #pragma unroll
  for (int rt = 0; rt < 5; ++rt){
    #pragma unroll
    for (int nt = 0; nt < 2; ++nt){
      int col = wv * 32 + nt * 16 + mr;
      float bv = bf2f(bias[col]);
      #pragma unroll
      for (int r4 = 0; r4 < 4; ++r4){
        int orow = lb * TM + rt * 16 + q * 4 + r4;
        float v = acc[rt][nt][r4] + bv;
        if (do_relu) v = fmaxf(v, 0.0f);
        unsigned short bits = f2bf(v);
        if constexpr (CMODE != 2) C[(size_t)orow * 128 + col] = bits;
        if constexpr (CMODE == 1)
          CM[((size_t)(col >> 4) * ncm + orow) * 16 + (col & 15)] = bits;
        if constexpr (CMODE == 2)
          CM[((size_t)(col >> 3) * ncm + orow) * 8 + (col & 7)] = bits;
      }
    }
  }
}

extern "C" void kernel_launch(void* const* d_in, const int* in_sizes, int n_in,
                              void* d_out, int out_size, void* d_ws, size_t ws_size,
                              hipStream_t stream)
{
  const void* raw[20];
  for (int i = 0; i < 20; ++i) raw[i] = d_in[i];
  const int* edge_occ   = (const int*)d_in[2];
  const int* edge_skill = (const int*)d_in[3];

  char* ws = (char*)d_ws;
  size_t off = 0;
  auto alloc = [&](size_t bytes) -> char* {
    char* p = ws + off;
    off = (off + bytes + 255) & ~(size_t)255;
    return p;
  };

  int* wire_flag = (int*)alloc(4);

  // canonical bf16 copies: x tensors (f32 wire only) + 16 weight tensors
  static const int cn[NT_CONV] = {
    N_OCC * D_IN, N_SKILL * D_IN,                // x_occ, x_skill (isx)
    D_IN * HID, HID, D_IN * HID, HID,            // pW_occ, pb_occ, pW_skill, pb_skill
    HID * HID, HID, HID * HID,                   // c1_os_Wl, bl, Wr
    HID * HID, HID, HID * HID,                   // c1_so_Wl, bl, Wr
    HID * OUT_F, OUT_F, HID * OUT_F,             // c2_os_Wl, bl, Wr
    HID * OUT_F, OUT_F, HID * OUT_F              // c2_so_Wl, bl, Wr
  };
  static const int raw_idx[NT_CONV] = {0,1, 4,5,6,7, 8,9,10, 11,12,13, 14,15,16, 17,18,19};
  static const int isx[NT_CONV]     = {1,1, 0,0,0,0, 0,0,0,  0,0,0,    0,0,0,    0,0,0};
  unsigned short* can[NT_CONV];
  for (int i = 0; i < NT_CONV; ++i) can[i] = (unsigned short*)alloc((size_t)cn[i] * 2);

  ConvTable ct;
  ct.blk_off[0] = 0;
  for (int i = 0; i < NT_CONV; ++i){
    ct.src[i] = raw[raw_idx[i]];
    ct.dst[i] = can[i];
    ct.n[i]   = cn[i];
    ct.isx[i] = isx[i];
    ct.blk_off[i + 1] = ct.blk_off[i] + (cn[i] + 2047) / 2048;
  }
  const int conv_blocks = ct.blk_off[NT_CONV];

  const unsigned short* can_xocc = can[0], *can_xskl = can[1];
  const unsigned short* c_pWo = can[2],  *c_pbo = can[3];
  const unsigned short* c_pWs = can[4],  *c_pbs = can[5];
  const unsigned short* c1osWl = can[6], *c1osbl = can[7], *c1osWr = can[8];
  const unsigned short* c1soWl = can[9], *c1sobl = can[10], *c1soWr = can[11];
  const unsigned short* c2osWl = can[12], *c2osbl = can[13], *c2osWr = can[14];
  const unsigned short* c2soWl = can[15], *c2sobl = can[16], *c2soWr = can[17];

  // transposed weights; conv2 weights land in combined [Wl | Wr] 128x128 blocks:
  //   comb_occ  rows 0..63 = c2_os_Wl^T, rows 64..127 = c2_so_Wr^T
  //   comb_skl  rows 0..63 = c2_so_Wl^T, rows 64..127 = c2_os_Wr^T
  unsigned short* wt_pocc   = (unsigned short*)alloc(32768 * 2);
  unsigned short* wt_pskill = (unsigned short*)alloc(32768 * 2);
  unsigned short* wt_c1osWl = (unsigned short*)alloc(16384 * 2);
  unsigned short* wt_c1osWr = (unsigned short*)alloc(16384 * 2);
  unsigned short* wt_c1soWl = (unsigned short*)alloc(16384 * 2);
  unsigned short* wt_c1soWr = (unsigned short*)alloc(16384 * 2);
  unsigned short* comb_occ  = (unsigned short*)alloc(16384 * 2);
  unsigned short* comb_skl  = (unsigned short*)alloc(16384 * 2);

  // zero-initialized region: bucket counts/cursors + zero bias
  size_t zero_bytes = (size_t)(2 * (NB_S + NB_O)) * 4 + 256;
  char* zero_base = alloc(zero_bytes);
  int* bkcnt_s = (int*)zero_base;
  int* bkcnt_o = bkcnt_s + NB_S;
  int* bcur_s  = bkcnt_o + NB_O;
  int* bcur_o  = bcur_s + NB_S;
  unsigned short* zbias = (unsigned short*)(bcur_o + NB_O);

  int* boff_s = (int*)alloc((NB_S + 1) * 4);
  int* boff_o = (int*)alloc((NB_O + 1) * 4);
  int* off_s = (int*)alloc((N_SKILL + 1) * 4);
  int* off_o = (int*)alloc((N_OCC + 1) * 4);
  int* csr_s = (int*)alloc((size_t)N_EDGE * 4);
  int* csr_o = (int*)alloc((size_t)N_EDGE * 4);
  unsigned* pair_s = (unsigned*)alloc((size_t)N_EDGE * 4);
  unsigned* pair_o = (unsigned*)alloc((size_t)N_EDGE * 4);

  unsigned short* h_occ    = (unsigned short*)alloc((size_t)N_OCC * HID * 2);
  unsigned short* h_skill  = (unsigned short*)alloc((size_t)N_SKILL * HID * 2);
  unsigned short* hcm_occ  = (unsigned short*)alloc((size_t)N_OCC * HID * 2);
  unsigned short* hcm_skl  = (unsigned short*)alloc((size_t)N_SKILL * HID * 2);
  unsigned short* mean_s   = (unsigned short*)alloc((size_t)N_SKILL * HID * 2);
  unsigned short* mean_o   = (unsigned short*)alloc((size_t)N_OCC * HID * 2);
  unsigned short* s1       = (unsigned short*)alloc((size_t)N_SKILL * HID * 2);
  unsigned short* o1       = (unsigned short*)alloc((size_t)N_OCC * HID * 2);
  unsigned short* Pcm_occ  = (unsigned short*)alloc((size_t)N_OCC * HID * 2);
  unsigned short* Pcm_skl  = (unsigned short*)alloc((size_t)N_SKILL * HID * 2);

  const int GT_OCC = N_OCC / 80;     // 250
  const int GT_SKL = N_SKILL / 80;   // 625
  const int SG_SKL = 8 * ((N_SKILL + 31) / 32);   // 12504 (mult of 8)
  const int SG_OCC = 8 * ((N_OCC + 31) / 32);     // 5000

  hipMemsetAsync(zero_base, 0, zero_bytes, stream);

  k_convert<<<conv_blocks, 256, 0, stream>>>(ct, (const unsigned short*)raw[0], wire_flag);

  k_transpose_all<<<640, 256, 0, stream>>>(
      c_pWo, wt_pocc, c_pWs, wt_pskill,
      c1osWl, wt_c1osWl, c1osWr, wt_c1osWr,
      c1soWl, wt_c1soWl, c1soWr, wt_c1soWr,
      c2osWl, comb_occ,              // -> comb_occ rows 0..63
      c2osWr, comb_skl + 64 * 128,   // -> comb_skl rows 64..127
      c2soWl, comb_skl,              // -> comb_skl rows 0..63
      c2soWr, comb_occ + 64 * 128);  // -> comb_occ rows 64..127

  // CSR build
  k_bincount<<<2 * BIN_BLKS, 256, 0, stream>>>(edge_occ, edge_skill, bkcnt_s, bkcnt_o);
  k_bscan<<<1, 128, 0, stream>>>(bkcnt_s, bkcnt_o, boff_s, boff_o, off_s, off_o);
  k_bin<<<2 * BIN_BLKS, 256, 0, stream>>>(edge_occ, edge_skill, boff_s, boff_o,
                                          bcur_s, bcur_o, pair_s, pair_o);
  k_build<<<NB_S + NB_O, 256, 0, stream>>>(pair_s, pair_o, boff_s, boff_o,
                                           off_s, off_o, csr_s, csr_o);

  // input projections + relu -> h (row-major, for conv1 staging) + h_cm (chunk-major, for gather)
  k_gemm4<256, 0, 1, 1><<<GT_OCC + GT_SKL, 256, 0, stream>>>(
      (const unsigned short*)raw[0], (const unsigned short*)raw[1],
      can_xocc, can_xskl,
      wt_pocc, wt_pskill, nullptr, nullptr, nullptr, nullptr,
      c_pbo, c_pbs, h_occ, h_skill, hcm_occ, hcm_skl, N_OCC, N_SKILL,
      GT_OCC, 1, wire_flag);

  // conv1 aggregation: XCD-sharded gather from chunk-major h
  k_seg_mean3<<<SG_SKL + SG_OCC, 256, 0, stream>>>(
      hcm_occ, off_s, csr_s, mean_s, N_SKILL, N_OCC, SG_SKL,
      hcm_skl, off_o, csr_o, mean_o, N_OCC, N_SKILL);

  // conv1 linear (both sides, one launch)
  k_gemm4<128, 1, 0, 0><<<GT_SKL + GT_OCC, 256, 0, stream>>>(
      mean_s, mean_o, mean_s, mean_o,
      wt_c1osWl, wt_c1soWl,
      h_skill, h_occ, wt_c1osWr, wt_c1soWr,
      c1osbl, c1sobl, s1, o1, nullptr, nullptr, 0, 0,
      GT_SKL, 1, wire_flag);

  // conv2: project BEFORE aggregating -> P chunk-major only
  //   P_occ = o1 @ [c2_os_Wl | c2_so_Wr],  P_skl = s1 @ [c2_so_Wl | c2_os_Wr]
  k_gemm4<128, 0, 0, 2><<<GT_OCC + GT_SKL, 256, 0, stream>>>(
      o1, s1, o1, s1,
      comb_occ, comb_skl, nullptr, nullptr, nullptr, nullptr,
      zbias, zbias, Pcm_occ, Pcm_skl, Pcm_occ, Pcm_skl, N_OCC, N_SKILL,
      GT_OCC, 0, wire_flag);

  // conv2 fused aggregate + self + bias -> wire output (XCD-sharded)
  // s2 (skill rows) at element offset N_OCC*64, o2 (occ rows) at offset 0
  k_seg_out3<<<SG_SKL + SG_OCC, 256, 0, stream>>>(
      Pcm_occ, Pcm_skl, off_s, csr_s, c2osbl, (size_t)N_OCC * OUT_F, N_SKILL, N_OCC, SG_SKL,
      Pcm_skl, Pcm_occ, off_o, csr_o, c2sobl, 0, N_OCC, N_SKILL,
      d_out, wire_flag);
}

// Round 10
// 316.841 us; speedup vs baseline: 1.1574x; 1.1574x over previous
//
#include <hip/hip_runtime.h>

#define N_OCC   20000
#define N_SKILL 50000
#define N_EDGE  600000
#define D_IN    256
#define HID     128
#define OUT_F   64

typedef short bf16x8 __attribute__((ext_vector_type(8)));
typedef float f32x4  __attribute__((ext_vector_type(4)));

__device__ __forceinline__ float bf2f(unsigned short u){
  return __uint_as_float(((unsigned)u) << 16);
}
__device__ __forceinline__ unsigned f2bf_bits(float f){
  unsigned i = __float_as_uint(f);
  return (i + 0x7fffu + ((i >> 16) & 1u)) >> 16;   // RNE
}
__device__ __forceinline__ unsigned f2bf_bits_u(unsigned i){
  return (i + 0x7fffu + ((i >> 16) & 1u)) >> 16;   // RNE from raw f32 bits
}
__device__ __forceinline__ unsigned short f2bf(float f){ return (unsigned short)f2bf_bits(f); }

// async global->LDS, 16B per lane. LDS dest must be linear in lane (wave-uniform
// base + lane*16); global src may be fully per-lane (m173: pre-swizzled source).
__device__ __forceinline__ void gload_lds16(const void* g, void* l){
  __builtin_amdgcn_global_load_lds(
      (const __attribute__((address_space(1))) unsigned int*)g,
      (__attribute__((address_space(3))) unsigned int*)l, 16, 0, 0);
}

// ---------- canonicalize float tensors to bf16 (self-detecting wire dtype) ----------
#define NT_CONV 18
struct ConvTable {
  const void*     src[NT_CONV];
  unsigned short* dst[NT_CONV];
  int             n[NT_CONV];
  int             isx[NT_CONV];
  int             blk_off[NT_CONV + 1];   // cumulative blocks (2048 elems/block)
};

__global__ void k_convert(ConvTable t, const unsigned short* __restrict__ xprobe,
                          int* __restrict__ flag){
  __shared__ int wsum[4];
  int tid = threadIdx.x;
  // self-detect: f32 low-mantissa halves have random exponent fields
  int cnt = 0;
  for (int i = tid; i < 1024; i += 256){
    unsigned e = ((unsigned)xprobe[i] >> 7) & 0xFFu;
    if (e >= 0xE0u) cnt++;
  }
  #pragma unroll
  for (int s = 1; s < 64; s <<= 1) cnt += __shfl_xor(cnt, s, 64);
  if ((tid & 63) == 0) wsum[tid >> 6] = cnt;
  __syncthreads();
  int isf32 = (wsum[0] + wsum[1] + wsum[2] + wsum[3]) >= 8;
  if (blockIdx.x == 0 && tid == 0) *flag = isf32;

  int b = blockIdx.x;
  int ti = 0;
  while (ti < NT_CONV - 1 && b >= t.blk_off[ti + 1]) ti++;
  if (!isf32 && t.isx[ti]) return;               // bf16 wire: x read in-place
  int lb = b - t.blk_off[ti];
  int i = (lb * 256 + tid) * 8;                  // element index (8 per thread)
  if (i >= t.n[ti]) return;
  unsigned short* dst = t.dst[ti];
  if (isf32){
    const float* s = (const float*)t.src[ti];
    uint4 lo = *(const uint4*)(s + i);
    uint4 hi = *(const uint4*)(s + i + 4);
    uint4 o;
    o.x = f2bf_bits_u(lo.x) | (f2bf_bits_u(lo.y) << 16);
    o.y = f2bf_bits_u(lo.z) | (f2bf_bits_u(lo.w) << 16);
    o.z = f2bf_bits_u(hi.x) | (f2bf_bits_u(hi.y) << 16);
    o.w = f2bf_bits_u(hi.z) | (f2bf_bits_u(hi.w) << 16);
    *(uint4*)(dst + i) = o;
  } else {
    *(uint4*)(dst + i) = *(const uint4*)((const unsigned short*)t.src[ti] + i);
  }
}

// ---------- transpose weight matrices W[K][N] -> WT[N][K] ----------
__global__ void k_transpose_all(
    const unsigned short* pWo, unsigned short* tWo,   // 256x128
    const unsigned short* pWs, unsigned short* tWs,   // 256x128
    const unsigned short* w2,  unsigned short* t2,    // 128x128
    const unsigned short* w3,  unsigned short* t3,
    const unsigned short* w4,  unsigned short* t4,
    const unsigned short* w5,  unsigned short* t5,
    const unsigned short* w6,  unsigned short* t6,    // 128x64
    const unsigned short* w7,  unsigned short* t7,
    const unsigned short* w8,  unsigned short* t8,
    const unsigned short* w9,  unsigned short* t9)
{
  int idx = blockIdx.x * blockDim.x + threadIdx.x;
  const unsigned short* in; unsigned short* out; int K, N, base;
  if      (idx <  32768){ in=pWo; out=tWo; K=256; N=128; base=0; }
  else if (idx <  65536){ in=pWs; out=tWs; K=256; N=128; base=32768; }
  else if (idx <  81920){ in=w2;  out=t2;  K=128; N=128; base=65536; }
  else if (idx <  98304){ in=w3;  out=t3;  K=128; N=128; base=81920; }
  else if (idx < 114688){ in=w4;  out=t4;  K=128; N=128; base=98304; }
  else if (idx < 131072){ in=w5;  out=t5;  K=128; N=128; base=114688; }
  else if (idx < 139264){ in=w6;  out=t6;  K=128; N=64;  base=131072; }
  else if (idx < 147456){ in=w7;  out=t7;  K=128; N=64;  base=139264; }
  else if (idx < 155648){ in=w8;  out=t8;  K=128; N=64;  base=147456; }
  else if (idx < 163840){ in=w9;  out=t9;  K=128; N=64;  base=155648; }
  else return;
  int li = idx - base;
  int k = li / N, n = li - k * N;
  out[n * K + k] = in[li];
}

// ---------- CSR build: bucket counting sort, no node-level global atomics ----------
#define EPB      4096
#define BIN_BLKS ((N_EDGE + EPB - 1) / EPB)         // 147
#define SH_S 9
#define SH_O 8
#define NB_S ((N_SKILL + (1 << SH_S) - 1) >> SH_S)  // 98
#define NB_O ((N_OCC   + (1 << SH_O) - 1) >> SH_O)  // 79

__launch_bounds__(256)
__global__ void k_bincount(const int* __restrict__ eo, const int* __restrict__ es,
                           int* __restrict__ bkcnt_s, int* __restrict__ bkcnt_o)
{
  int b = blockIdx.x;
  int side = (b >= BIN_BLKS) ? 1 : 0;
  int lb = side ? b - BIN_BLKS : b;
  const int* dste = side ? eo : es;
  int* bkcnt = side ? bkcnt_o : bkcnt_s;
  const int NB = side ? NB_O : NB_S;
  const int SH = side ? SH_O : SH_S;
  __shared__ int cntL[NB_S];
  for (int i = threadIdx.x; i < NB; i += 256) cntL[i] = 0;
  __syncthreads();
  int e0 = lb * EPB, e1 = min(e0 + EPB, N_EDGE);
  for (int e = e0 + threadIdx.x; e < e1; e += 256)
    atomicAdd(&cntL[dste[e] >> SH], 1);
  __syncthreads();
  for (int i = threadIdx.x; i < NB; i += 256)
    if (cntL[i]) atomicAdd(&bkcnt[i], cntL[i]);
}

__global__ void k_bscan(const int* __restrict__ bkcnt_s, const int* __restrict__ bkcnt_o,
                        int* __restrict__ boff_s, int* __restrict__ boff_o,
                        int* __restrict__ off_s, int* __restrict__ off_o)
{
  __shared__ int sc[128];
  int t = threadIdx.x;   // 128 threads
  int v = (t < NB_S) ? bkcnt_s[t] : 0;
  sc[t] = v;
  __syncthreads();
  for (int d = 1; d < 128; d <<= 1){
    int u = (t >= d) ? sc[t - d] : 0;
    __syncthreads();
    sc[t] += u;
    __syncthreads();
  }
  if (t < NB_S) boff_s[t] = sc[t] - v;
  if (t == 0){ boff_s[NB_S] = N_EDGE; off_s[N_SKILL] = N_EDGE; }
  __syncthreads();
  int v2 = (t < NB_O) ? bkcnt_o[t] : 0;
  sc[t] = v2;
  __syncthreads();
  for (int d = 1; d < 128; d <<= 1){
    int u = (t >= d) ? sc[t - d] : 0;
    __syncthreads();
    sc[t] += u;
    __syncthreads();
  }
  if (t < NB_O) boff_o[t] = sc[t] - v2;
  if (t == 0){ boff_o[NB_O] = N_EDGE; off_o[N_OCC] = N_EDGE; }
}

// packed pair: (local_dst << 16) | src   (src < 65536, local_dst < 512)
__launch_bounds__(256)
__global__ void k_bin(const int* __restrict__ eo, const int* __restrict__ es,
                      const int* __restrict__ boff_s, const int* __restrict__ boff_o,
                      int* __restrict__ bcur_s, int* __restrict__ bcur_o,
                      unsigned* __restrict__ pair_s, unsigned* __restrict__ pair_o)
{
  int b = blockIdx.x;
  int side = (b >= BIN_BLKS) ? 1 : 0;
  int lb = side ? b - BIN_BLKS : b;
  const int* dste = side ? eo : es;
  const int* srce = side ? es : eo;
  const int* boff = side ? boff_o : boff_s;
  int* bcur       = side ? bcur_o : bcur_s;
  unsigned* pairs = side ? pair_o : pair_s;
  const int NB = side ? NB_O : NB_S;
  const int SH = side ? SH_O : SH_S;

  __shared__ int cntL[NB_S], gbaseL[NB_S], lbaseL[NB_S], runL[NB_S];
  __shared__ int sc[128];
  __shared__ unsigned stage[EPB];   // 16 KB
  __shared__ int gpos[EPB];         // 16 KB

  int e0 = lb * EPB;
  int e1 = min(e0 + EPB, N_EDGE);

  for (int i = threadIdx.x; i < NB; i += 256){ cntL[i] = 0; runL[i] = 0; }
  __syncthreads();
  for (int e = e0 + threadIdx.x; e < e1; e += 256)
    atomicAdd(&cntL[dste[e] >> SH], 1);
  __syncthreads();
  if (threadIdx.x < 128) sc[threadIdx.x] = (threadIdx.x < NB) ? cntL[threadIdx.x] : 0;
  __syncthreads();
  for (int d = 1; d < 128; d <<= 1){
    int v = 0;
    if (threadIdx.x < 128 && threadIdx.x >= d) v = sc[threadIdx.x - d];
    __syncthreads();
    if (threadIdx.x < 128) sc[threadIdx.x] += v;
    __syncthreads();
  }
  if (threadIdx.x < NB){
    int c = cntL[threadIdx.x];
    lbaseL[threadIdx.x] = sc[threadIdx.x] - c;
    gbaseL[threadIdx.x] = boff[threadIdx.x] + atomicAdd(&bcur[threadIdx.x], c);
  }
  __syncthreads();
  for (int e = e0 + threadIdx.x; e < e1; e += 256){
    int d = dste[e], s = srce[e];
    int bk = d >> SH;
    int r = atomicAdd(&runL[bk], 1);
    int lp = lbaseL[bk] + r;
    stage[lp] = ((unsigned)(d & ((1 << SH) - 1)) << 16) | (unsigned)s;
    gpos[lp] = gbaseL[bk] + r;
  }
  __syncthreads();
  int tot = e1 - e0;
  for (int i = threadIdx.x; i < tot; i += 256)
    pairs[gpos[i]] = stage[i];     // consecutive within each bucket run -> coalesced
}

__launch_bounds__(256)
__global__ void k_build(const unsigned* __restrict__ pair_s, const unsigned* __restrict__ pair_o,
                        const int* __restrict__ boff_s, const int* __restrict__ boff_o,
                        int* __restrict__ off_s, int* __restrict__ off_o,
                        int* __restrict__ csr_s, int* __restrict__ csr_o)
{
  int b = blockIdx.x;
  int side = (b >= NB_S) ? 1 : 0;
  int lb = side ? b - NB_S : b;
  const unsigned* pairs = side ? pair_o : pair_s;
  const int* boff = side ? boff_o : boff_s;
  int* off = side ? off_o : off_s;
  int* csr = side ? csr_o : csr_s;
  int SH = side ? SH_O : SH_S;
  int nd_tot = side ? N_OCC : N_SKILL;
  int d0 = lb << SH;
  int d1 = min(d0 + (1 << SH), nd_tot);
  int nd = d1 - d0;
  int p0 = boff[lb], p1 = boff[lb + 1];

  __shared__ int cntL[1 << SH_S];
  __shared__ int offL[1 << SH_S];
  __shared__ int ws[4];
  int t = threadIdx.x;
  cntL[t] = 0; cntL[t + 256] = 0;
  __syncthreads();
  for (int i = p0 + t; i < p1; i += 256)
    atomicAdd(&cntL[pairs[i] >> 16], 1);
  __syncthreads();
  int a0 = cntL[2 * t], a1 = cntL[2 * t + 1];
  int s = a0 + a1;
  int lane = t & 63, wv = t >> 6;
  int x = s;
  #pragma unroll
  for (int d = 1; d < 64; d <<= 1){ int u = __shfl_up(x, d, 64); if (lane >= d) x += u; }
  if (lane == 63) ws[wv] = x;
  __syncthreads();
  int woff = 0;
  for (int w = 0; w < wv; ++w) woff += ws[w];
  int excl = woff + x - s;
  offL[2 * t] = excl;
  offL[2 * t + 1] = excl + a0;
  __syncthreads();
  for (int i = t; i < nd; i += 256) off[d0 + i] = p0 + offL[i];
  cntL[t] = 0; cntL[t + 256] = 0;
  __syncthreads();
  for (int i = p0 + t; i < p1; i += 256){
    unsigned pr = pairs[i];
    int d = (int)(pr >> 16);
    int p = p0 + offL[d] + atomicAdd(&cntL[d], 1);
    csr[p] = (int)(pr & 0xFFFFu);   // scattered only within one L2-resident window
  }
}

// ---------- fused-pair segment mean: one wave per dst node, 128 bf16 feats ----------
// 2x-unrolled edge loop: both csr loads then both gathers issued together --
// halves the serial csr->gather round-trips (r9 lesson: latency-bound chain).
__launch_bounds__(256)
__global__ void k_seg_mean2(const unsigned short* __restrict__ feat0,
                            const int* __restrict__ off0, const int* __restrict__ csr0,
                            unsigned short* __restrict__ out0, int n0, int nb0,
                            const unsigned short* __restrict__ feat1,
                            const int* __restrict__ off1, const int* __restrict__ csr1,
                            unsigned short* __restrict__ out1, int n1)
{
  int b = blockIdx.x;
  int side = (b >= nb0) ? 1 : 0;
  const unsigned short* feat = side ? feat1 : feat0;
  const int* off = side ? off1 : off0;
  const int* csr = side ? csr1 : csr0;
  unsigned short* out = side ? out1 : out0;
  int n_dst = side ? n1 : n0;
  int gw = (side ? b - nb0 : b) * 4 + (int)(threadIdx.x >> 6);
  if (gw >= n_dst) return;
  int lane = threadIdx.x & 63;
  int r = lane >> 4;
  int c = lane & 15;
  int beg = off[gw], end = off[gw + 1];
  const unsigned short* fc = feat + (c << 3);
  float acc[8];
  #pragma unroll
  for (int j = 0; j < 8; ++j) acc[j] = 0.0f;
  int e = beg + r;
  for (; e + 4 < end; e += 8){
    int s0 = csr[e];
    int s1 = csr[e + 4];
    uint4 v0 = *(const uint4*)(fc + ((size_t)s0 << 7));
    uint4 v1 = *(const uint4*)(fc + ((size_t)s1 << 7));
    acc[0] += __uint_as_float(v0.x << 16);          acc[1] += __uint_as_float(v0.x & 0xffff0000u);
    acc[2] += __uint_as_float(v0.y << 16);          acc[3] += __uint_as_float(v0.y & 0xffff0000u);
    acc[4] += __uint_as_float(v0.z << 16);          acc[5] += __uint_as_float(v0.z & 0xffff0000u);
    acc[6] += __uint_as_float(v0.w << 16);          acc[7] += __uint_as_float(v0.w & 0xffff0000u);
    acc[0] += __uint_as_float(v1.x << 16);          acc[1] += __uint_as_float(v1.x & 0xffff0000u);
    acc[2] += __uint_as_float(v1.y << 16);          acc[3] += __uint_as_float(v1.y & 0xffff0000u);
    acc[4] += __uint_as_float(v1.z << 16);          acc[5] += __uint_as_float(v1.z & 0xffff0000u);
    acc[6] += __uint_as_float(v1.w << 16);          acc[7] += __uint_as_float(v1.w & 0xffff0000u);
  }
  if (e < end){
    int s0 = csr[e];
    uint4 v = *(const uint4*)(fc + ((size_t)s0 << 7));
    acc[0] += __uint_as_float(v.x << 16); acc[1] += __uint_as_float(v.x & 0xffff0000u);
    acc[2] += __uint_as_float(v.y << 16); acc[3] += __uint_as_float(v.y & 0xffff0000u);
    acc[4] += __uint_as_float(v.z << 16); acc[5] += __uint_as_float(v.z & 0xffff0000u);
    acc[6] += __uint_as_float(v.w << 16); acc[7] += __uint_as_float(v.w & 0xffff0000u);
  }
  #pragma unroll
  for (int j = 0; j < 8; ++j){
    acc[j] += __shfl_xor(acc[j], 16, 64);
    acc[j] += __shfl_xor(acc[j], 32, 64);
  }
  if (r == 0){
    int cnt = end - beg;
    float inv = 1.0f / (float)(cnt > 0 ? cnt : 1);
    uint4 o;
    o.x = f2bf_bits(acc[0] * inv) | (f2bf_bits(acc[1] * inv) << 16);
    o.y = f2bf_bits(acc[2] * inv) | (f2bf_bits(acc[3] * inv) << 16);
    o.z = f2bf_bits(acc[4] * inv) | (f2bf_bits(acc[5] * inv) << 16);
    o.w = f2bf_bits(acc[6] * inv) | (f2bf_bits(acc[7] * inv) << 16);
    *(uint4*)(out + ((size_t)gw << 7) + (c << 3)) = o;
  }
}

// ---------- fused-pair conv2 output: mean_gather(Pg[:,0:64]) + Ps[d,64:128] + bias ----------
// 2x-unrolled edge loop (occ side deg~30 -> ~4 serial iters without it).
__launch_bounds__(256)
__global__ void k_seg_out2(const unsigned short* __restrict__ Pg0, const unsigned short* __restrict__ Ps0,
                           const int* __restrict__ off0, const int* __restrict__ csr0,
                           const unsigned short* __restrict__ bias0, size_t o_off0, int n0, int nb0,
                           const unsigned short* __restrict__ Pg1, const unsigned short* __restrict__ Ps1,
                           const int* __restrict__ off1, const int* __restrict__ csr1,
                           const unsigned short* __restrict__ bias1, size_t o_off1, int n1,
                           void* __restrict__ out, const int* __restrict__ wire_flag)
{
  int b = blockIdx.x;
  int side = (b >= nb0) ? 1 : 0;
  const unsigned short* Pg = side ? Pg1 : Pg0;
  const unsigned short* Ps = side ? Ps1 : Ps0;
  const int* off = side ? off1 : off0;
  const int* csr = side ? csr1 : csr0;
  const unsigned short* bias = side ? bias1 : bias0;
  size_t o_off = side ? o_off1 : o_off0;
  int n_dst = side ? n1 : n0;
  int gw = (side ? b - nb0 : b) * 4 + (int)(threadIdx.x >> 6);
  if (gw >= n_dst) return;
  int lane = threadIdx.x & 63;
  int r = lane >> 3;          // 8 edge groups
  int c = lane & 7;           // 8 chunks of 8 bf16 = 64 feats
  int beg = off[gw], end = off[gw + 1];
  const unsigned short* gc = Pg + (c << 3);
  float acc[8];
  #pragma unroll
  for (int j = 0; j < 8; ++j) acc[j] = 0.0f;
  int e = beg + r;
  for (; e + 8 < end; e += 16){
    int s0 = csr[e];
    int s1 = csr[e + 8];
    uint4 v0 = *(const uint4*)(gc + ((size_t)s0 << 7));
    uint4 v1 = *(const uint4*)(gc + ((size_t)s1 << 7));
    acc[0] += __uint_as_float(v0.x << 16);          acc[1] += __uint_as_float(v0.x & 0xffff0000u);
    acc[2] += __uint_as_float(v0.y << 16);          acc[3] += __uint_as_float(v0.y & 0xffff0000u);
    acc[4] += __uint_as_float(v0.z << 16);          acc[5] += __uint_as_float(v0.z & 0xffff0000u);
    acc[6] += __uint_as_float(v0.w << 16);          acc[7] += __uint_as_float(v0.w & 0xffff0000u);
    acc[0] += __uint_as_float(v1.x << 16);          acc[1] += __uint_as_float(v1.x & 0xffff0000u);
    acc[2] += __uint_as_float(v1.y << 16);          acc[3] += __uint_as_float(v1.y & 0xffff0000u);
    acc[4] += __uint_as_float(v1.z << 16);          acc[5] += __uint_as_float(v1.z & 0xffff0000u);
    acc[6] += __uint_as_float(v1.w << 16);          acc[7] += __uint_as_float(v1.w & 0xffff0000u);
  }
  if (e < end){
    int s0 = csr[e];
    uint4 v = *(const uint4*)(gc + ((size_t)s0 << 7));
    acc[0] += __uint_as_float(v.x << 16); acc[1] += __uint_as_float(v.x & 0xffff0000u);
    acc[2] += __uint_as_float(v.y << 16); acc[3] += __uint_as_float(v.y & 0xffff0000u);
    acc[4] += __uint_as_float(v.z << 16); acc[5] += __uint_as_float(v.z & 0xffff0000u);
    acc[6] += __uint_as_float(v.w << 16); acc[7] += __uint_as_float(v.w & 0xffff0000u);
  }
  #pragma unroll
  for (int j = 0; j < 8; ++j){
    acc[j] += __shfl_xor(acc[j], 8, 64);
    acc[j] += __shfl_xor(acc[j], 16, 64);
    acc[j] += __shfl_xor(acc[j], 32, 64);
  }
  if (r == 0){
    int cnt = end - beg;
    float inv = 1.0f / (float)(cnt > 0 ? cnt : 1);
    uint4 sv = *(const uint4*)(Ps + ((size_t)gw << 7) + 64 + (c << 3));
    uint4 bv = *(const uint4*)(bias + (c << 3));
    float o0 = acc[0] * inv + __uint_as_float(sv.x << 16)         + __uint_as_float(bv.x << 16);
    float o1 = acc[1] * inv + __uint_as_float(sv.x & 0xffff0000u) + __uint_as_float(bv.x & 0xffff0000u);
    float o2 = acc[2] * inv + __uint_as_float(sv.y << 16)         + __uint_as_float(bv.y << 16);
    float o3 = acc[3] * inv + __uint_as_float(sv.y & 0xffff0000u) + __uint_as_float(bv.y & 0xffff0000u);
    float o4 = acc[4] * inv + __uint_as_float(sv.z << 16)         + __uint_as_float(bv.z << 16);
    float o5 = acc[5] * inv + __uint_as_float(sv.z & 0xffff0000u) + __uint_as_float(bv.z & 0xffff0000u);
    float o6 = acc[6] * inv + __uint_as_float(sv.w << 16)         + __uint_as_float(bv.w << 16);
    float o7 = acc[7] * inv + __uint_as_float(sv.w & 0xffff0000u) + __uint_as_float(bv.w & 0xffff0000u);
    size_t eoff = o_off + (size_t)gw * 64 + (c << 3);
    if (*wire_flag){
      float* op = (float*)out + eoff;
      uint4 w0, w1;
      w0.x = __float_as_uint(o0); w0.y = __float_as_uint(o1);
      w0.z = __float_as_uint(o2); w0.w = __float_as_uint(o3);
      w1.x = __float_as_uint(o4); w1.y = __float_as_uint(o5);
      w1.z = __float_as_uint(o6); w1.w = __float_as_uint(o7);
      *(uint4*)op = w0;
      *(uint4*)(op + 4) = w1;
    } else {
      unsigned short* op = (unsigned short*)out + eoff;
      uint4 w;
      w.x = f2bf_bits(o0) | (f2bf_bits(o1) << 16);
      w.y = f2bf_bits(o2) | (f2bf_bits(o3) << 16);
      w.z = f2bf_bits(o4) | (f2bf_bits(o5) << 16);
      w.w = f2bf_bits(o6) | (f2bf_bits(o7) << 16);
      *(uint4*)op = w;
    }
  }
}

// ---------- LDS-staged fused-pair GEMM (r8 structure) ----------
template<int K1, int HASA2, int AW>
__launch_bounds__(256)
__global__ void k_gemm4(const unsigned short* __restrict__ A1a_0, const unsigned short* __restrict__ A1a_1,
                        const unsigned short* __restrict__ A1b_0, const unsigned short* __restrict__ A1b_1,
                        const unsigned short* __restrict__ W1T_0, const unsigned short* __restrict__ W1T_1,
                        const unsigned short* __restrict__ A2_0, const unsigned short* __restrict__ A2_1,
                        const unsigned short* __restrict__ W2T_0, const unsigned short* __restrict__ W2T_1,
                        const unsigned short* __restrict__ bias_0, const unsigned short* __restrict__ bias_1,
                        unsigned short* __restrict__ C_0, unsigned short* __restrict__ C_1,
                        int nb0, int do_relu, const int* __restrict__ wire_flag)
{
  constexpr int TM    = 80;
  constexpr int ROWB  = K1 * 2;            // bytes per row
  constexpr int TILEB = TM * ROWB;         // bytes per staged tensor tile
  constexpr int ITERS = TILEB / 4096;      // 16B x 256 threads per iter
  constexpr int NK    = K1 / 32;
  constexpr int RSH   = (K1 == 256) ? 9 : 8;

  __shared__ unsigned short lds[(HASA2 ? 2 : 1) * TM * K1];

  int b = blockIdx.x;
  int side = (b >= nb0) ? 1 : 0;
  int lb = side ? b - nb0 : b;
  const unsigned short* A1a = side ? A1a_1 : A1a_0;
  const unsigned short* A1b = side ? A1b_1 : A1b_0;
  const unsigned short* W1T = side ? W1T_1 : W1T_0;
  const unsigned short* A2  = side ? A2_1  : A2_0;
  const unsigned short* W2T = side ? W2T_1 : W2T_0;
  const unsigned short* bias= side ? bias_1: bias_0;
  unsigned short* C = side ? C_1 : C_0;

  const unsigned short* A1 = (AW && *wire_flag) ? A1b : A1a;   // f32 wire -> canonical bf16
  const int tid = threadIdx.x;

  // ---- stage A tiles (linear LDS, swizzled global source) ----
  {
    const char* a1base = (const char*)A1 + (size_t)lb * TILEB;
    #pragma unroll
    for (int it = 0; it < ITERS; ++it){
      int L = (it * 256 + tid) * 16;
      int row = L >> RSH;
      int cb  = L & (ROWB - 1);
      int gb  = row * ROWB + (cb ^ ((row & 7) << 4));
      gload_lds16(a1base + gb, (char*)lds + L);
    }
    if (HASA2){
      const char* a2base = (const char*)A2 + (size_t)lb * TILEB;
      #pragma unroll
      for (int it = 0; it < ITERS; ++it){
        int L = (it * 256 + tid) * 16;
        int row = L >> RSH;
        int cb  = L & (ROWB - 1);
        int gb  = row * ROWB + (cb ^ ((row & 7) << 4));
        gload_lds16(a2base + gb, (char*)lds + TILEB + L);
      }
    }
  }

  // ---- B fragments from L2 (overlap the staging drain) ----
  const int lane = tid & 63;
  const int wv   = tid >> 6;       // 32-col group per wave
  const int q    = lane >> 4;
  const int mr   = lane & 15;
  const int koff = q * 8;          // elements

  bf16x8 b1[2][NK];
  #pragma unroll
  for (int nt = 0; nt < 2; ++nt){
    const unsigned short* bp = W1T + (size_t)(wv * 32 + nt * 16 + mr) * K1 + koff;
    #pragma unroll
    for (int k = 0; k < NK; ++k)
      b1[nt][k] = *(const bf16x8*)(bp + k * 32);
  }
  bf16x8 b2[2][HASA2 ? NK : 1];
  if (HASA2){
    #pragma unroll
    for (int nt = 0; nt < 2; ++nt){
      const unsigned short* bp = W2T + (size_t)(wv * 32 + nt * 16 + mr) * K1 + koff;
      #pragma unroll
      for (int k = 0; k < NK; ++k)
        b2[nt][k] = *(const bf16x8*)(bp + k * 32);
    }
  }

  __syncthreads();   // drains vmcnt (incl. global_load_lds) then barrier

  // ---- LDS -> MFMA: 5 row-tiles x 2 col-tiles ----
  f32x4 acc[5][2];
  #pragma unroll
  for (int rt = 0; rt < 5; ++rt)
    #pragma unroll
    for (int nt = 0; nt < 2; ++nt)
      #pragma unroll
      for (int j = 0; j < 4; ++j) acc[rt][nt][j] = 0.0f;

  #pragma unroll
  for (int rt = 0; rt < 5; ++rt){
    const int rl = rt * 16 + mr;
    const int sw = (rl & 7) << 4;
    #pragma unroll
    for (int k = 0; k < NK; ++k){
      const int cb = k * 64 + q * 16;               // bytes within row
      bf16x8 a = *(const bf16x8*)((const char*)lds + rl * ROWB + (cb ^ sw));
      #pragma unroll
      for (int nt = 0; nt < 2; ++nt)
        acc[rt][nt] = __builtin_amdgcn_mfma_f32_16x16x32_bf16(a, b1[nt][k], acc[rt][nt], 0, 0, 0);
      if (HASA2){
        bf16x8 a2 = *(const bf16x8*)((const char*)lds + TILEB + rl * ROWB + (cb ^ sw));
        #pragma unroll
        for (int nt = 0; nt < 2; ++nt)
          acc[rt][nt] = __builtin_amdgcn_mfma_f32_16x16x32_bf16(a2, b2[nt][k], acc[rt][nt], 0, 0, 0);
      }
    }
  }

  // ---- epilogue (no row guards: M % 80 == 0) ----
  #pragma unroll
  for (int rt = 0; rt < 5; ++rt){
    #pragma unroll
    for (int nt = 0; nt < 2; ++nt){
      int col = wv * 32 + nt * 16 + mr;
      float bv = bf2f(bias[col]);
      #pragma unroll
      for (int r4 = 0; r4 < 4; ++r4){
        int orow = lb * TM + rt * 16 + q * 4 + r4;
        float v = acc[rt][nt][r4] + bv;
        if (do_relu) v = fmaxf(v, 0.0f);
        C[(size_t)orow * 128 + col] = f2bf(v);
      }
    }
  }
}

extern "C" void kernel_launch(void* const* d_in, const int* in_sizes, int n_in,
                              void* d_out, int out_size, void* d_ws, size_t ws_size,
                              hipStream_t stream)
{
  const void* raw[20];
  for (int i = 0; i < 20; ++i) raw[i] = d_in[i];
  const int* edge_occ   = (const int*)d_in[2];
  const int* edge_skill = (const int*)d_in[3];

  char* ws = (char*)d_ws;
  size_t off = 0;
  auto alloc = [&](size_t bytes) -> char* {
    char* p = ws + off;
    off = (off + bytes + 255) & ~(size_t)255;
    return p;
  };

  int* wire_flag = (int*)alloc(4);

  // canonical bf16 copies: x tensors (f32 wire only) + 16 weight tensors
  static const int cn[NT_CONV] = {
    N_OCC * D_IN, N_SKILL * D_IN,                // x_occ, x_skill (isx)
    D_IN * HID, HID, D_IN * HID, HID,            // pW_occ, pb_occ, pW_skill, pb_skill
    HID * HID, HID, HID * HID,                   // c1_os_Wl, bl, Wr
    HID * HID, HID, HID * HID,                   // c1_so_Wl, bl, Wr
    HID * OUT_F, OUT_F, HID * OUT_F,             // c2_os_Wl, bl, Wr
    HID * OUT_F, OUT_F, HID * OUT_F              // c2_so_Wl, bl, Wr
  };
  static const int raw_idx[NT_CONV] = {0,1, 4,5,6,7, 8,9,10, 11,12,13, 14,15,16, 17,18,19};
  static const int isx[NT_CONV]     = {1,1, 0,0,0,0, 0,0,0,  0,0,0,    0,0,0,    0,0,0};
  unsigned short* can[NT_CONV];
  for (int i = 0; i < NT_CONV; ++i) can[i] = (unsigned short*)alloc((size_t)cn[i] * 2);

  ConvTable ct;
  ct.blk_off[0] = 0;
  for (int i = 0; i < NT_CONV; ++i){
    ct.src[i] = raw[raw_idx[i]];
    ct.dst[i] = can[i];
    ct.n[i]   = cn[i];
    ct.isx[i] = isx[i];
    ct.blk_off[i + 1] = ct.blk_off[i] + (cn[i] + 2047) / 2048;
  }
  const int conv_blocks = ct.blk_off[NT_CONV];

  const unsigned short* can_xocc = can[0], *can_xskl = can[1];
  const unsigned short* c_pWo = can[2],  *c_pbo = can[3];
  const unsigned short* c_pWs = can[4],  *c_pbs = can[5];
  const unsigned short* c1osWl = can[6], *c1osbl = can[7], *c1osWr = can[8];
  const unsigned short* c1soWl = can[9], *c1sobl = can[10], *c1soWr = can[11];
  const unsigned short* c2osWl = can[12], *c2osbl = can[13], *c2osWr = can[14];
  const unsigned short* c2soWl = can[15], *c2sobl = can[16], *c2soWr = can[17];

  // transposed weights; conv2 weights land in combined [Wl | Wr] 128x128 blocks:
  //   comb_occ  rows 0..63 = c2_os_Wl^T, rows 64..127 = c2_so_Wr^T
  //   comb_skl  rows 0..63 = c2_so_Wl^T, rows 64..127 = c2_os_Wr^T
  unsigned short* wt_pocc   = (unsigned short*)alloc(32768 * 2);
  unsigned short* wt_pskill = (unsigned short*)alloc(32768 * 2);
  unsigned short* wt_c1osWl = (unsigned short*)alloc(16384 * 2);
  unsigned short* wt_c1osWr = (unsigned short*)alloc(16384 * 2);
  unsigned short* wt_c1soWl = (unsigned short*)alloc(16384 * 2);
  unsigned short* wt_c1soWr = (unsigned short*)alloc(16384 * 2);
  unsigned short* comb_occ  = (unsigned short*)alloc(16384 * 2);
  unsigned short* comb_skl  = (unsigned short*)alloc(16384 * 2);

  // zero-initialized region: bucket counts/cursors + zero bias
  size_t zero_bytes = (size_t)(2 * (NB_S + NB_O)) * 4 + 256;
  char* zero_base = alloc(zero_bytes);
  int* bkcnt_s = (int*)zero_base;
  int* bkcnt_o = bkcnt_s + NB_S;
  int* bcur_s  = bkcnt_o + NB_O;
  int* bcur_o  = bcur_s + NB_S;
  unsigned short* zbias = (unsigned short*)(bcur_o + NB_O);

  int* boff_s = (int*)alloc((NB_S + 1) * 4);
  int* boff_o = (int*)alloc((NB_O + 1) * 4);
  int* off_s = (int*)alloc((N_SKILL + 1) * 4);
  int* off_o = (int*)alloc((N_OCC + 1) * 4);
  int* csr_s = (int*)alloc((size_t)N_EDGE * 4);
  int* csr_o = (int*)alloc((size_t)N_EDGE * 4);
  unsigned* pair_s = (unsigned*)alloc((size_t)N_EDGE * 4);
  unsigned* pair_o = (unsigned*)alloc((size_t)N_EDGE * 4);

  unsigned short* h_occ   = (unsigned short*)alloc((size_t)N_OCC * HID * 2);
  unsigned short* h_skill = (unsigned short*)alloc((size_t)N_SKILL * HID * 2);
  unsigned short* mean_s  = (unsigned short*)alloc((size_t)N_SKILL * HID * 2);
  unsigned short* mean_o  = (unsigned short*)alloc((size_t)N_OCC * HID * 2);
  unsigned short* s1      = (unsigned short*)alloc((size_t)N_SKILL * HID * 2);
  unsigned short* o1      = (unsigned short*)alloc((size_t)N_OCC * HID * 2);
  unsigned short* P_occ   = (unsigned short*)alloc((size_t)N_OCC * HID * 2);
  unsigned short* P_skl   = (unsigned short*)alloc((size_t)N_SKILL * HID * 2);

  const int GT_OCC = N_OCC / 80;     // 250
  const int GT_SKL = N_SKILL / 80;   // 625
  const int SM_SKL = (N_SKILL + 3) / 4;
  const int SM_OCC = (N_OCC + 3) / 4;

  hipMemsetAsync(zero_base, 0, zero_bytes, stream);

  k_convert<<<conv_blocks, 256, 0, stream>>>(ct, (const unsigned short*)raw[0], wire_flag);

  k_transpose_all<<<640, 256, 0, stream>>>(
      c_pWo, wt_pocc, c_pWs, wt_pskill,
      c1osWl, wt_c1osWl, c1osWr, wt_c1osWr,
      c1soWl, wt_c1soWl, c1soWr, wt_c1soWr,
      c2osWl, comb_occ,              // -> comb_occ rows 0..63
      c2osWr, comb_skl + 64 * 128,   // -> comb_skl rows 64..127
      c2soWl, comb_skl,              // -> comb_skl rows 0..63
      c2soWr, comb_occ + 64 * 128);  // -> comb_occ rows 64..127

  // CSR build
  k_bincount<<<2 * BIN_BLKS, 256, 0, stream>>>(edge_occ, edge_skill, bkcnt_s, bkcnt_o);
  k_bscan<<<1, 128, 0, stream>>>(bkcnt_s, bkcnt_o, boff_s, boff_o, off_s, off_o);
  k_bin<<<2 * BIN_BLKS, 256, 0, stream>>>(edge_occ, edge_skill, boff_s, boff_o,
                                          bcur_s, bcur_o, pair_s, pair_o);
  k_build<<<NB_S + NB_O, 256, 0, stream>>>(pair_s, pair_o, boff_s, boff_o,
                                           off_s, off_o, csr_s, csr_o);

  // input projections + relu (bf16 wire read in-place; f32 wire -> canonical copy)
  k_gemm4<256, 0, 1><<<GT_OCC + GT_SKL, 256, 0, stream>>>(
      (const unsigned short*)raw[0], (const unsigned short*)raw[1],
      can_xocc, can_xskl,
      wt_pocc, wt_pskill, nullptr, nullptr, nullptr, nullptr,
      c_pbo, c_pbs, h_occ, h_skill, GT_OCC, 1, wire_flag);

  // conv1 aggregation (both sides, one launch)
  k_seg_mean2<<<SM_SKL + SM_OCC, 256, 0, stream>>>(
      h_occ, off_s, csr_s, mean_s, N_SKILL, SM_SKL,
      h_skill, off_o, csr_o, mean_o, N_OCC);

  // conv1 linear (both sides, one launch)
  k_gemm4<128, 1, 0><<<GT_SKL + GT_OCC, 256, 0, stream>>>(
      mean_s, mean_o, mean_s, mean_o,
      wt_c1osWl, wt_c1soWl,
      h_skill, h_occ, wt_c1osWr, wt_c1soWr,
      c1osbl, c1sobl, s1, o1, GT_SKL, 1, wire_flag);

  // conv2: project BEFORE aggregating (mean and linear commute):
  //   P_occ = o1 @ [c2_os_Wl | c2_so_Wr],  P_skl = s1 @ [c2_so_Wl | c2_os_Wr]
  k_gemm4<128, 0, 0><<<GT_OCC + GT_SKL, 256, 0, stream>>>(
      o1, s1, o1, s1,
      comb_occ, comb_skl, nullptr, nullptr, nullptr, nullptr,
      zbias, zbias, P_occ, P_skl, GT_OCC, 0, wire_flag);

  // conv2 fused aggregate + self + bias -> wire output (both sides, one launch)
  // s2 (skill rows) at element offset N_OCC*64, o2 (occ rows) at offset 0
  k_seg_out2<<<SM_SKL + SM_OCC, 256, 0, stream>>>(
      P_occ, P_skl, off_s, csr_s, c2osbl, (size_t)N_OCC * OUT_F, N_SKILL, SM_SKL,
      P_skl, P_occ, off_o, csr_o, c2sobl, 0, N_OCC,
      d_out, wire_flag);
}